// Round 1
// baseline (4269.761 us; speedup 1.0000x reference)
//
#include <hip/hip_runtime.h>
#include <math.h>

#define NN 250000
#define NE 4000000
#define NG 512
#define HD 16

// ---- ordered-uint encoding for float atomicMax ----
__device__ __forceinline__ unsigned enc(float f) {
    unsigned u = __float_as_uint(f);
    return (u & 0x80000000u) ? ~u : (u | 0x80000000u);
}
__device__ __forceinline__ float dec(unsigned u) {
    return __uint_as_float((u & 0x80000000u) ? (u ^ 0x80000000u) : ~u);
}

// ---- fold we into last edge-MLP layer: ew3p = ew3@we, eb3p = eb3@we ----
__global__ __launch_bounds__(256) void k_fold(
    const float* __restrict__ ew3, const float* __restrict__ eb3,
    const float* __restrict__ we, float* __restrict__ ew3p, float* __restrict__ eb3p)
{
    int t = threadIdx.x;           // 0..255
    int j = t >> 4, k = t & 15;
    float acc = 0.f;
    for (int l = 0; l < HD; ++l) acc += ew3[j * HD + l] * we[l * HD + k];
    ew3p[t] = acc;
    if (j == 0) {
        float b = 0.f;
        for (int l = 0; l < HD; ++l) b += eb3[l] * we[l * HD + k];
        eb3p[k] = b;
    }
}

// ---- node MLP + GAT lin_l/lin_r, fused ----
__global__ __launch_bounds__(256) void k_node(
    const float* __restrict__ x,
    const float* __restrict__ nw1, const float* __restrict__ nb1,
    const float* __restrict__ nw2, const float* __restrict__ nb2,
    const float* __restrict__ nw3, const float* __restrict__ nb3,
    const float* __restrict__ wl, const float* __restrict__ bl,
    const float* __restrict__ wr, const float* __restrict__ br,
    float* __restrict__ xl, float* __restrict__ xr)
{
    int i = blockIdx.x * 256 + threadIdx.x;
    if (i >= NN) return;
    float4 xv = reinterpret_cast<const float4*>(x)[i];
    float a0 = xv.x, a1 = xv.y, a2 = xv.z, a3 = xv.w;
    float h1[HD], h2[HD], h3[HD];
#pragma unroll
    for (int k = 0; k < HD; ++k) {
        float acc = nb1[k] + a0 * nw1[0 * HD + k] + a1 * nw1[1 * HD + k]
                  + a2 * nw1[2 * HD + k] + a3 * nw1[3 * HD + k];
        h1[k] = fmaxf(acc, 0.f);
    }
#pragma unroll
    for (int k = 0; k < HD; ++k) {
        float acc = nb2[k];
#pragma unroll
        for (int j = 0; j < HD; ++j) acc += h1[j] * nw2[j * HD + k];
        h2[k] = fmaxf(acc, 0.f);
    }
#pragma unroll
    for (int k = 0; k < HD; ++k) {
        float acc = nb3[k];
#pragma unroll
        for (int j = 0; j < HD; ++j) acc += h2[j] * nw3[j * HD + k];
        h3[k] = acc;
    }
    float xlv[HD], xrv[HD];
#pragma unroll
    for (int k = 0; k < HD; ++k) {
        float al = bl[k], ar = br[k];
#pragma unroll
        for (int j = 0; j < HD; ++j) { al += h3[j] * wl[j * HD + k]; ar += h3[j] * wr[j * HD + k]; }
        xlv[k] = al; xrv[k] = ar;
    }
    float4* xlo = reinterpret_cast<float4*>(xl + (size_t)i * HD);
    float4* xro = reinterpret_cast<float4*>(xr + (size_t)i * HD);
#pragma unroll
    for (int q = 0; q < 4; ++q) {
        xlo[q] = make_float4(xlv[4*q], xlv[4*q+1], xlv[4*q+2], xlv[4*q+3]);
        xro[q] = make_float4(xrv[4*q], xrv[4*q+1], xrv[4*q+2], xrv[4*q+3]);
    }
}

// ---- edge MLP (folded) + attention logit s, atomicMax m[dst], block partial of ew ----
__global__ __launch_bounds__(256) void k_edge1(
    const float* __restrict__ ea, const int* __restrict__ ei,
    const float* __restrict__ ew1, const float* __restrict__ eb1,
    const float* __restrict__ ew2, const float* __restrict__ eb2,
    const float* __restrict__ ew3p, const float* __restrict__ eb3p,
    const float* __restrict__ att,
    const float* __restrict__ xl, const float* __restrict__ xr,
    float* __restrict__ s_out, unsigned* __restrict__ m_u,
    float* __restrict__ partial)
{
    int e = blockIdx.x * 256 + threadIdx.x;
    float ew[HD];
#pragma unroll
    for (int k = 0; k < HD; ++k) ew[k] = 0.f;

    if (e < NE) {
        float4 av0 = reinterpret_cast<const float4*>(ea)[(size_t)e * 2];
        float4 av1 = reinterpret_cast<const float4*>(ea)[(size_t)e * 2 + 1];
        float a[8] = {av0.x, av0.y, av0.z, av0.w, av1.x, av1.y, av1.z, av1.w};
        float t1[HD], t2[HD];
#pragma unroll
        for (int k = 0; k < HD; ++k) {
            float acc = eb1[k];
#pragma unroll
            for (int c = 0; c < 8; ++c) acc += a[c] * ew1[c * HD + k];
            t1[k] = fmaxf(acc, 0.f);
        }
#pragma unroll
        for (int k = 0; k < HD; ++k) {
            float acc = eb2[k];
#pragma unroll
            for (int j = 0; j < HD; ++j) acc += t1[j] * ew2[j * HD + k];
            t2[k] = fmaxf(acc, 0.f);
        }
#pragma unroll
        for (int k = 0; k < HD; ++k) {
            float acc = eb3p[k];
#pragma unroll
            for (int j = 0; j < HD; ++j) acc += t2[j] * ew3p[j * HD + k];
            ew[k] = acc;
        }
        int src = ei[e];
        int dst = ei[NE + e];
        const float4* xls = reinterpret_cast<const float4*>(xl + (size_t)src * HD);
        const float4* xrs = reinterpret_cast<const float4*>(xr + (size_t)dst * HD);
        float xlv[HD], xrv[HD];
#pragma unroll
        for (int q = 0; q < 4; ++q) {
            float4 lv = xls[q]; xlv[4*q]=lv.x; xlv[4*q+1]=lv.y; xlv[4*q+2]=lv.z; xlv[4*q+3]=lv.w;
            float4 rv = xrs[q]; xrv[4*q]=rv.x; xrv[4*q+1]=rv.y; xrv[4*q+2]=rv.z; xrv[4*q+3]=rv.w;
        }
        float s = 0.f;
#pragma unroll
        for (int k = 0; k < HD; ++k) {
            float t = xlv[k] + xrv[k] + ew[k];
            t = t > 0.f ? t : 0.2f * t;
            s += t * att[k];
        }
        s_out[e] = s;
        atomicMax(&m_u[dst], enc(s));
    }

    // block-level partial sum of ew (for mean over edges)
    for (int off = 32; off > 0; off >>= 1) {
#pragma unroll
        for (int k = 0; k < HD; ++k) ew[k] += __shfl_xor(ew[k], off);
    }
    __shared__ float bsum[HD];
    if (threadIdx.x < HD) bsum[threadIdx.x] = 0.f;
    __syncthreads();
    if ((threadIdx.x & 63) == 0) {
#pragma unroll
        for (int k = 0; k < HD; ++k) atomicAdd(&bsum[k], ew[k]);
    }
    __syncthreads();
    if (threadIdx.x < HD) partial[(size_t)blockIdx.x * HD + threadIdx.x] = bsum[threadIdx.x];
}

// ---- reduce block partials -> ewm = mean(e)@we ----
__global__ __launch_bounds__(256) void k_redp(
    const float* __restrict__ partial, int nblk, float* __restrict__ ewm)
{
    __shared__ float red[256];
    int t = threadIdx.x;
    int k = t & 15, c = t >> 4;
    float acc = 0.f;
    for (int b = c; b < nblk; b += 16) acc += partial[(size_t)b * HD + k];
    red[t] = acc;
    __syncthreads();
    if (t < HD) {
        float s = 0.f;
        for (int c2 = 0; c2 < 16; ++c2) s += red[c2 * 16 + t];
        ewm[t] = s * (1.f / (float)NE);
    }
}

// ---- self-loop logit, merge into m ----
__global__ __launch_bounds__(256) void k_self(
    const float* __restrict__ xl, const float* __restrict__ xr,
    const float* __restrict__ ewm, const float* __restrict__ att,
    float* __restrict__ s_self, unsigned* __restrict__ m_u)
{
    int i = blockIdx.x * 256 + threadIdx.x;
    if (i >= NN) return;
    const float4* xls = reinterpret_cast<const float4*>(xl + (size_t)i * HD);
    const float4* xrs = reinterpret_cast<const float4*>(xr + (size_t)i * HD);
    float s = 0.f;
#pragma unroll
    for (int q = 0; q < 4; ++q) {
        float4 lv = xls[q]; float4 rv = xrs[q];
        float t;
        t = lv.x + rv.x + ewm[4*q+0]; t = t > 0.f ? t : 0.2f * t; s += t * att[4*q+0];
        t = lv.y + rv.y + ewm[4*q+1]; t = t > 0.f ? t : 0.2f * t; s += t * att[4*q+1];
        t = lv.z + rv.z + ewm[4*q+2]; t = t > 0.f ? t : 0.2f * t; s += t * att[4*q+2];
        t = lv.w + rv.w + ewm[4*q+3]; t = t > 0.f ? t : 0.2f * t; s += t * att[4*q+3];
    }
    s_self[i] = s;
    unsigned es = enc(s);
    unsigned cur = m_u[i];
    m_u[i] = cur > es ? cur : es;
}

// ---- softmax accumulate: den[dst] += p, outacc[dst] += p*xl[src] ----
__global__ __launch_bounds__(256) void k_edge2(
    const int* __restrict__ ei, const float* __restrict__ s_in,
    const unsigned* __restrict__ m_u, const float* __restrict__ xl,
    float* __restrict__ den, float* __restrict__ outacc)
{
    int e = blockIdx.x * 256 + threadIdx.x;
    if (e >= NE) return;
    int src = ei[e], dst = ei[NE + e];
    float m = dec(m_u[dst]);
    float p = __expf(s_in[e] - m);
    atomicAdd(&den[dst], p);
    const float4* xls = reinterpret_cast<const float4*>(xl + (size_t)src * HD);
    float* ob = outacc + (size_t)dst * HD;
#pragma unroll
    for (int q = 0; q < 4; ++q) {
        float4 lv = xls[q];
        atomicAdd(ob + 4*q + 0, p * lv.x);
        atomicAdd(ob + 4*q + 1, p * lv.y);
        atomicAdd(ob + 4*q + 2, p * lv.z);
        atomicAdd(ob + 4*q + 3, p * lv.w);
    }
}

// ---- node finalize + segmented global-max-pool (batch sorted) ----
__global__ __launch_bounds__(256) void k_nodefin(
    const float* __restrict__ xl, const float* __restrict__ s_self,
    const unsigned* __restrict__ m_u, const float* __restrict__ den,
    const float* __restrict__ outacc, const float* __restrict__ gat_bias,
    const int* __restrict__ batch, unsigned* __restrict__ pooled_u)
{
    int i = blockIdx.x * 256 + threadIdx.x;
    bool valid = i < NN;
    int b = -1;
    float o[HD];
#pragma unroll
    for (int k = 0; k < HD; ++k) o[k] = -3.4e38f;
    if (valid) {
        float m = dec(m_u[i]);
        float p = __expf(s_self[i] - m);
        float d = den[i] + p;
        float inv = 1.f / d;
        const float4* oa = reinterpret_cast<const float4*>(outacc + (size_t)i * HD);
        const float4* xls = reinterpret_cast<const float4*>(xl + (size_t)i * HD);
#pragma unroll
        for (int q = 0; q < 4; ++q) {
            float4 av = oa[q]; float4 lv = xls[q];
            o[4*q+0] = (av.x + p * lv.x) * inv + gat_bias[4*q+0];
            o[4*q+1] = (av.y + p * lv.y) * inv + gat_bias[4*q+1];
            o[4*q+2] = (av.z + p * lv.z) * inv + gat_bias[4*q+2];
            o[4*q+3] = (av.w + p * lv.w) * inv + gat_bias[4*q+3];
        }
        b = batch[i];
    }
    int lane = threadIdx.x & 63;
    // segmented max-reduce within wave (batch sorted => segments contiguous)
    for (int off = 1; off < 64; off <<= 1) {
        int nb = __shfl_down(b, off);
        bool merge = (lane + off < 64) && (nb == b);
#pragma unroll
        for (int k = 0; k < HD; ++k) {
            float ov = __shfl_down(o[k], off);
            if (merge) o[k] = fmaxf(o[k], ov);
        }
    }
    int bprev = __shfl_up(b, 1);
    bool head = (lane == 0) || (bprev != b);
    if (valid && head && b >= 0) {
#pragma unroll
        for (int k = 0; k < HD; ++k) atomicMax(&pooled_u[b * HD + k], enc(o[k]));
    }
}

// ---- head MLP + BatchNorm + LeakyReLU + Linear + sigmoid, one block of 512 ----
__global__ __launch_bounds__(512) void k_final(
    const unsigned* __restrict__ pooled_u,
    const float* __restrict__ ow1, const float* __restrict__ ob1,
    const float* __restrict__ gam, const float* __restrict__ bet,
    const float* __restrict__ ow2, const float* __restrict__ ob2,
    float* __restrict__ out)
{
    int g = threadIdx.x; // 0..511, one per graph
    float pv[HD], z[HD];
#pragma unroll
    for (int k = 0; k < HD; ++k) pv[k] = dec(pooled_u[g * HD + k]);
#pragma unroll
    for (int k = 0; k < HD; ++k) {
        float acc = ob1[k];
#pragma unroll
        for (int j = 0; j < HD; ++j) acc += pv[j] * ow1[j * HD + k];
        z[k] = acc;
    }
    float s1[HD], s2[HD];
#pragma unroll
    for (int k = 0; k < HD; ++k) { s1[k] = z[k]; s2[k] = z[k] * z[k]; }
    for (int off = 32; off > 0; off >>= 1) {
#pragma unroll
        for (int k = 0; k < HD; ++k) {
            s1[k] += __shfl_xor(s1[k], off);
            s2[k] += __shfl_xor(s2[k], off);
        }
    }
    __shared__ float red1[HD], red2[HD];
    if (g < HD) { red1[g] = 0.f; red2[g] = 0.f; }
    __syncthreads();
    if ((g & 63) == 0) {
#pragma unroll
        for (int k = 0; k < HD; ++k) { atomicAdd(&red1[k], s1[k]); atomicAdd(&red2[k], s2[k]); }
    }
    __syncthreads();
    float acc2 = ob2[0];
#pragma unroll
    for (int k = 0; k < HD; ++k) {
        float mu = red1[k] * (1.f / (float)NG);
        float var = red2[k] * (1.f / (float)NG) - mu * mu;
        float zn = (z[k] - mu) * rsqrtf(var + 1e-5f) * gam[k] + bet[k];
        zn = zn > 0.f ? zn : 0.01f * zn;
        acc2 += zn * ow2[k];
    }
    out[g] = acc2;
    out[NG + g] = 1.f / (1.f + __expf(-acc2));
}

extern "C" void kernel_launch(void* const* d_in, const int* in_sizes, int n_in,
                              void* d_out, int out_size, void* d_ws, size_t ws_size,
                              hipStream_t stream)
{
    const float* x     = (const float*)d_in[0];
    const int*   ei    = (const int*)d_in[1];
    const int*   batch = (const int*)d_in[2];
    const float* ea    = (const float*)d_in[3];
    // d_in[4] = num_graphs (512, fixed)
    const float* nw1 = (const float*)d_in[5],  *nb1 = (const float*)d_in[6];
    const float* nw2 = (const float*)d_in[7],  *nb2 = (const float*)d_in[8];
    const float* nw3 = (const float*)d_in[9],  *nb3 = (const float*)d_in[10];
    const float* ew1 = (const float*)d_in[11], *eb1 = (const float*)d_in[12];
    const float* ew2 = (const float*)d_in[13], *eb2 = (const float*)d_in[14];
    const float* ew3 = (const float*)d_in[15], *eb3 = (const float*)d_in[16];
    const float* wl  = (const float*)d_in[17], *bl  = (const float*)d_in[18];
    const float* wr  = (const float*)d_in[19], *br  = (const float*)d_in[20];
    const float* we  = (const float*)d_in[21], *att = (const float*)d_in[22];
    const float* gat_bias = (const float*)d_in[23];
    const float* ow1 = (const float*)d_in[24], *ob1 = (const float*)d_in[25];
    const float* gam = (const float*)d_in[26], *bet = (const float*)d_in[27];
    const float* ow2 = (const float*)d_in[28], *ob2 = (const float*)d_in[29];

    const int NBLK_E = NE / 256;            // 15625, exact
    const int NBLK_N = (NN + 255) / 256;    // 977

    float* ws     = (float*)d_ws;
    float* xl     = ws;                               // 16N
    float* xr     = xl + (size_t)16 * NN;             // 16N
    float* s_e    = xr + (size_t)16 * NN;             // E
    float* s_self = s_e + (size_t)NE;                 // N
    float* partial= s_self + (size_t)NN;              // NBLK_E*16
    float* ew3p   = partial + (size_t)NBLK_E * HD;    // 256
    float* eb3p   = ew3p + 256;                       // 16
    float* ewm    = eb3p + 16;                        // 16
    float* zero0  = ewm + 16;                         // ---- zero region ----
    float* outacc = zero0;                            // 16N
    float* den    = outacc + (size_t)16 * NN;         // N
    unsigned* m_u = (unsigned*)(den + (size_t)NN);    // N
    unsigned* pooled_u = m_u + (size_t)NN;            // NG*HD

    size_t zero_bytes = ((size_t)16 * NN + NN + NN + (size_t)NG * HD) * sizeof(float);
    hipMemsetAsync(zero0, 0, zero_bytes, stream);

    k_fold<<<1, 256, 0, stream>>>(ew3, eb3, we, ew3p, eb3p);
    k_node<<<NBLK_N, 256, 0, stream>>>(x, nw1, nb1, nw2, nb2, nw3, nb3, wl, bl, wr, br, xl, xr);
    k_edge1<<<NBLK_E, 256, 0, stream>>>(ea, ei, ew1, eb1, ew2, eb2, ew3p, eb3p, att, xl, xr, s_e, m_u, partial);
    k_redp<<<1, 256, 0, stream>>>(partial, NBLK_E, ewm);
    k_self<<<NBLK_N, 256, 0, stream>>>(xl, xr, ewm, att, s_self, m_u);
    k_edge2<<<NBLK_E, 256, 0, stream>>>(ei, s_e, m_u, xl, den, outacc);
    k_nodefin<<<NBLK_N, 256, 0, stream>>>(xl, s_self, m_u, den, outacc, gat_bias, batch, pooled_u);
    k_final<<<1, 512, 0, stream>>>(pooled_u, ow1, ob1, gam, bet, ow2, ob2, (float*)d_out);
}

// Round 3
// 1096.719 us; speedup vs baseline: 3.8932x; 3.8932x over previous
//
#include <hip/hip_runtime.h>
#include <math.h>

#define NN 250000
#define NE 4000000
#define NG 512
#define HD 16
#define SCB 245   // ceil(NN/1024) scan blocks

// ---- ordered-uint encoding for float atomicMax ----
__device__ __forceinline__ unsigned enc(float f) {
    unsigned u = __float_as_uint(f);
    return (u & 0x80000000u) ? ~u : (u | 0x80000000u);
}
__device__ __forceinline__ float dec(unsigned u) {
    return __uint_as_float((u & 0x80000000u) ? (u ^ 0x80000000u) : ~u);
}

// ---- fold we into last edge-MLP layer: ew3p = ew3@we, eb3p = eb3@we ----
__global__ __launch_bounds__(256) void k_fold(
    const float* __restrict__ ew3, const float* __restrict__ eb3,
    const float* __restrict__ we, float* __restrict__ ew3p, float* __restrict__ eb3p)
{
    int t = threadIdx.x;
    int j = t >> 4, k = t & 15;
    float acc = 0.f;
    for (int l = 0; l < HD; ++l) acc += ew3[j * HD + l] * we[l * HD + k];
    ew3p[t] = acc;
    if (j == 0) {
        float b = 0.f;
        for (int l = 0; l < HD; ++l) b += eb3[l] * we[l * HD + k];
        eb3p[k] = b;
    }
}

// ---- node MLP + GAT lin_l/lin_r, fused ----
__global__ __launch_bounds__(256) void k_node(
    const float* __restrict__ x,
    const float* __restrict__ nw1, const float* __restrict__ nb1,
    const float* __restrict__ nw2, const float* __restrict__ nb2,
    const float* __restrict__ nw3, const float* __restrict__ nb3,
    const float* __restrict__ wl, const float* __restrict__ bl,
    const float* __restrict__ wr, const float* __restrict__ br,
    float* __restrict__ xl, float* __restrict__ xr)
{
    int i = blockIdx.x * 256 + threadIdx.x;
    if (i >= NN) return;
    float4 xv = reinterpret_cast<const float4*>(x)[i];
    float a0 = xv.x, a1 = xv.y, a2 = xv.z, a3 = xv.w;
    float h1[HD], h2[HD], h3[HD];
#pragma unroll
    for (int k = 0; k < HD; ++k) {
        float acc = nb1[k] + a0 * nw1[0 * HD + k] + a1 * nw1[1 * HD + k]
                  + a2 * nw1[2 * HD + k] + a3 * nw1[3 * HD + k];
        h1[k] = fmaxf(acc, 0.f);
    }
#pragma unroll
    for (int k = 0; k < HD; ++k) {
        float acc = nb2[k];
#pragma unroll
        for (int j = 0; j < HD; ++j) acc += h1[j] * nw2[j * HD + k];
        h2[k] = fmaxf(acc, 0.f);
    }
#pragma unroll
    for (int k = 0; k < HD; ++k) {
        float acc = nb3[k];
#pragma unroll
        for (int j = 0; j < HD; ++j) acc += h2[j] * nw3[j * HD + k];
        h3[k] = acc;
    }
    float xlv[HD], xrv[HD];
#pragma unroll
    for (int k = 0; k < HD; ++k) {
        float al = bl[k], ar = br[k];
#pragma unroll
        for (int j = 0; j < HD; ++j) { al += h3[j] * wl[j * HD + k]; ar += h3[j] * wr[j * HD + k]; }
        xlv[k] = al; xrv[k] = ar;
    }
    float4* xlo = reinterpret_cast<float4*>(xl + (size_t)i * HD);
    float4* xro = reinterpret_cast<float4*>(xr + (size_t)i * HD);
#pragma unroll
    for (int q = 0; q < 4; ++q) {
        xlo[q] = make_float4(xlv[4*q], xlv[4*q+1], xlv[4*q+2], xlv[4*q+3]);
        xro[q] = make_float4(xrv[4*q], xrv[4*q+1], xrv[4*q+2], xrv[4*q+3]);
    }
}

// ---- degree histogram ----
__global__ __launch_bounds__(256) void k_count(const int* __restrict__ ei, int* __restrict__ deg)
{
    int e = blockIdx.x * 256 + threadIdx.x;
    if (e < NE) atomicAdd(&deg[ei[NE + e]], 1);
}

// ---- hierarchical exclusive scan: deg -> rowptr (+cursor copy) ----
__global__ __launch_bounds__(256) void k_scan1(const int* __restrict__ deg, int* __restrict__ bsum)
{
    int b = blockIdx.x, t = threadIdx.x;
    int base = b * 1024 + t * 4;
    int s = 0;
#pragma unroll
    for (int q = 0; q < 4; ++q) { int idx = base + q; if (idx < NN) s += deg[idx]; }
    for (int off = 1; off < 64; off <<= 1) s += __shfl_xor(s, off);
    __shared__ int wsum[4];
    if ((t & 63) == 0) wsum[t >> 6] = s;
    __syncthreads();
    if (t == 0) bsum[b] = wsum[0] + wsum[1] + wsum[2] + wsum[3];
}

__global__ __launch_bounds__(256) void k_scan2(const int* __restrict__ bsum, int* __restrict__ bscan)
{
    int t = threadIdx.x;
    int v = (t < SCB) ? bsum[t] : 0;
    int incl = v;
    int lane = t & 63, w = t >> 6;
    for (int off = 1; off < 64; off <<= 1) { int u = __shfl_up(incl, off); if (lane >= off) incl += u; }
    __shared__ int wsum[4];
    if (lane == 63) wsum[w] = incl;
    __syncthreads();
    int add = 0;
    for (int q = 0; q < w; ++q) add += wsum[q];
    if (t < SCB) bscan[t] = incl + add - v;   // exclusive
}

__global__ __launch_bounds__(256) void k_scan3(const int* __restrict__ deg, const int* __restrict__ bscan,
                                               int* __restrict__ rowptr, int* __restrict__ cursor)
{
    int b = blockIdx.x, t = threadIdx.x;
    int base = b * 1024 + t * 4;
    int d[4]; int s = 0;
#pragma unroll
    for (int q = 0; q < 4; ++q) { int idx = base + q; d[q] = (idx < NN) ? deg[idx] : 0; s += d[q]; }
    int lane = t & 63, w = t >> 6;
    int incl = s;
    for (int off = 1; off < 64; off <<= 1) { int u = __shfl_up(incl, off); if (lane >= off) incl += u; }
    __shared__ int wsum[4];
    if (lane == 63) wsum[w] = incl;
    __syncthreads();
    int add = bscan[b];
    for (int q = 0; q < w; ++q) add += wsum[q];
    int ex = add + incl - s;
#pragma unroll
    for (int q = 0; q < 4; ++q) {
        int idx = base + q;
        if (idx < NN) { rowptr[idx] = ex; cursor[idx] = ex; }
        ex += d[q];
    }
}

// ---- edge MLP (folded) + attention logit, scatter (src,s) into CSR slot ----
__global__ __launch_bounds__(256) void k_edge1(
    const float* __restrict__ ea, const int* __restrict__ ei,
    const float* __restrict__ ew1, const float* __restrict__ eb1,
    const float* __restrict__ ew2, const float* __restrict__ eb2,
    const float* __restrict__ ew3p, const float* __restrict__ eb3p,
    const float* __restrict__ att,
    const float* __restrict__ xl, const float* __restrict__ xr,
    int* __restrict__ cursor, uint2* __restrict__ edval,
    float* __restrict__ partial)
{
    int e = blockIdx.x * 256 + threadIdx.x;
    float ew[HD];
#pragma unroll
    for (int k = 0; k < HD; ++k) ew[k] = 0.f;

    if (e < NE) {
        float4 av0 = reinterpret_cast<const float4*>(ea)[(size_t)e * 2];
        float4 av1 = reinterpret_cast<const float4*>(ea)[(size_t)e * 2 + 1];
        float a[8] = {av0.x, av0.y, av0.z, av0.w, av1.x, av1.y, av1.z, av1.w};
        float t1[HD], t2[HD];
#pragma unroll
        for (int k = 0; k < HD; ++k) {
            float acc = eb1[k];
#pragma unroll
            for (int c = 0; c < 8; ++c) acc += a[c] * ew1[c * HD + k];
            t1[k] = fmaxf(acc, 0.f);
        }
#pragma unroll
        for (int k = 0; k < HD; ++k) {
            float acc = eb2[k];
#pragma unroll
            for (int j = 0; j < HD; ++j) acc += t1[j] * ew2[j * HD + k];
            t2[k] = fmaxf(acc, 0.f);
        }
#pragma unroll
        for (int k = 0; k < HD; ++k) {
            float acc = eb3p[k];
#pragma unroll
            for (int j = 0; j < HD; ++j) acc += t2[j] * ew3p[j * HD + k];
            ew[k] = acc;
        }
        int src = ei[e];
        int dst = ei[NE + e];
        const float4* xls = reinterpret_cast<const float4*>(xl + (size_t)src * HD);
        const float4* xrs = reinterpret_cast<const float4*>(xr + (size_t)dst * HD);
        float s = 0.f;
#pragma unroll
        for (int q = 0; q < 4; ++q) {
            float4 lv = xls[q]; float4 rv = xrs[q];
            float t;
            t = lv.x + rv.x + ew[4*q+0]; t = t > 0.f ? t : 0.2f * t; s += t * att[4*q+0];
            t = lv.y + rv.y + ew[4*q+1]; t = t > 0.f ? t : 0.2f * t; s += t * att[4*q+1];
            t = lv.z + rv.z + ew[4*q+2]; t = t > 0.f ? t : 0.2f * t; s += t * att[4*q+2];
            t = lv.w + rv.w + ew[4*q+3]; t = t > 0.f ? t : 0.2f * t; s += t * att[4*q+3];
        }
        int pos = atomicAdd(&cursor[dst], 1);
        edval[pos] = make_uint2((unsigned)src, __float_as_uint(s));
    }

    // block-level partial sum of ew (for mean over edges)
    for (int off = 32; off > 0; off >>= 1) {
#pragma unroll
        for (int k = 0; k < HD; ++k) ew[k] += __shfl_xor(ew[k], off);
    }
    __shared__ float bsumf[HD];
    if (threadIdx.x < HD) bsumf[threadIdx.x] = 0.f;
    __syncthreads();
    if ((threadIdx.x & 63) == 0) {
#pragma unroll
        for (int k = 0; k < HD; ++k) atomicAdd(&bsumf[k], ew[k]);
    }
    __syncthreads();
    if (threadIdx.x < HD) partial[(size_t)blockIdx.x * HD + threadIdx.x] = bsumf[threadIdx.x];
}

// ---- reduce block partials -> ewm = mean(e)@we ----
__global__ __launch_bounds__(256) void k_redp(
    const float* __restrict__ partial, int nblk, float* __restrict__ ewm)
{
    __shared__ float red[256];
    int t = threadIdx.x;
    int k = t & 15, c = t >> 4;
    float acc = 0.f;
    for (int b = c; b < nblk; b += 16) acc += partial[(size_t)b * HD + k];
    red[t] = acc;
    __syncthreads();
    if (t < HD) {
        float s = 0.f;
        for (int c2 = 0; c2 < 16; ++c2) s += red[c2 * 16 + t];
        ewm[t] = s * (1.f / (float)NE);
    }
}

// ---- pull-style softmax + aggregate: 16 lanes per node, no atomics ----
// NOTE: outn aliases xr. Safe: xr[i*16+k] is read only at thread start by the
// exact lane that later writes outn[i*16+k]; no cross-node xr reads here.
__global__ __launch_bounds__(256) void k_gather(
    const uint2* __restrict__ edval, const int* __restrict__ rowptr, const int* __restrict__ deg,
    const float* __restrict__ xl, const float* __restrict__ xr,
    const float* __restrict__ ewm, const float* __restrict__ att,
    const float* __restrict__ gat_bias, float* __restrict__ outn)
{
    int t = threadIdx.x;
    int lane = t & 63;
    int sub = lane >> 4;            // group within wave
    int k = lane & 15;              // component
    int wid = t >> 6;               // wave within block
    int i = blockIdx.x * 16 + wid * 4 + sub;   // 15625*16 == NN exactly

    float xlk = xl[(size_t)i * HD + k];
    float tv = xlk + xr[(size_t)i * HD + k] + ewm[k];
    tv = tv > 0.f ? tv : 0.2f * tv;
    float term = tv * att[k];
#pragma unroll
    for (int off = 1; off < 16; off <<= 1) term += __shfl_xor(term, off);
    float s_self = term;

    int start = rowptr[i], cnt = deg[i];

    // pass 1: per-node max of s (incl. self)
    float mmax = s_self;
    for (int base = 0; base < cnt; base += 16) {
        int j = base + k;
        float sv = -3.4e38f;
        if (j < cnt) sv = __uint_as_float(edval[start + j].y);
        mmax = fmaxf(mmax, sv);
    }
#pragma unroll
    for (int off = 1; off < 16; off <<= 1) mmax = fmaxf(mmax, __shfl_xor(mmax, off));

    // pass 2: den + weighted aggregate
    float p_self = __expf(s_self - mmax);
    float denl = 0.f;
    float acc = p_self * xlk;
    int basel = lane & 48;          // sub*16
    for (int base = 0; base < cnt; base += 16) {
        int j = base + k;
        int srcv = 0; float pv = 0.f;
        if (j < cnt) {
            uint2 v = edval[start + j];
            srcv = (int)v.x;
            pv = __expf(__uint_as_float(v.y) - mmax);
        }
        denl += pv;
#pragma unroll
        for (int tlo = 0; tlo < 16; ++tlo) {
            int src_t = __shfl(srcv, basel + tlo);
            float p_t = __shfl(pv, basel + tlo);
            acc += p_t * xl[(size_t)src_t * HD + k];
        }
    }
#pragma unroll
    for (int off = 1; off < 16; off <<= 1) denl += __shfl_xor(denl, off);
    float den = denl + p_self;
    outn[(size_t)i * HD + k] = acc / den + gat_bias[k];
}

// ---- segmented global-max-pool (batch sorted) ----
__global__ __launch_bounds__(256) void k_pool(
    const float* __restrict__ outn, const int* __restrict__ batch,
    unsigned* __restrict__ pooled_u)
{
    int i = blockIdx.x * 256 + threadIdx.x;
    bool valid = i < NN;
    int b = -1;
    float o[HD];
#pragma unroll
    for (int k = 0; k < HD; ++k) o[k] = -3.4e38f;
    if (valid) {
        const float4* ov = reinterpret_cast<const float4*>(outn + (size_t)i * HD);
#pragma unroll
        for (int q = 0; q < 4; ++q) {
            float4 v = ov[q];
            o[4*q+0] = v.x; o[4*q+1] = v.y; o[4*q+2] = v.z; o[4*q+3] = v.w;
        }
        b = batch[i];
    }
    int lane = threadIdx.x & 63;
    for (int off = 1; off < 64; off <<= 1) {
        int nb = __shfl_down(b, off);
        bool merge = (lane + off < 64) && (nb == b);
#pragma unroll
        for (int k = 0; k < HD; ++k) {
            float ov2 = __shfl_down(o[k], off);
            if (merge) o[k] = fmaxf(o[k], ov2);
        }
    }
    int bprev = __shfl_up(b, 1);
    bool head = (lane == 0) || (bprev != b);
    if (valid && head && b >= 0) {
#pragma unroll
        for (int k = 0; k < HD; ++k) atomicMax(&pooled_u[b * HD + k], enc(o[k]));
    }
}

// ---- head MLP + BatchNorm + LeakyReLU + Linear + sigmoid ----
__global__ __launch_bounds__(512) void k_final(
    const unsigned* __restrict__ pooled_u,
    const float* __restrict__ ow1, const float* __restrict__ ob1,
    const float* __restrict__ gam, const float* __restrict__ bet,
    const float* __restrict__ ow2, const float* __restrict__ ob2,
    float* __restrict__ out)
{
    int g = threadIdx.x;
    float pv[HD], z[HD];
#pragma unroll
    for (int k = 0; k < HD; ++k) pv[k] = dec(pooled_u[g * HD + k]);
#pragma unroll
    for (int k = 0; k < HD; ++k) {
        float acc = ob1[k];
#pragma unroll
        for (int j = 0; j < HD; ++j) acc += pv[j] * ow1[j * HD + k];
        z[k] = acc;
    }
    float s1[HD], s2[HD];
#pragma unroll
    for (int k = 0; k < HD; ++k) { s1[k] = z[k]; s2[k] = z[k] * z[k]; }
    for (int off = 32; off > 0; off >>= 1) {
#pragma unroll
        for (int k = 0; k < HD; ++k) {
            s1[k] += __shfl_xor(s1[k], off);
            s2[k] += __shfl_xor(s2[k], off);
        }
    }
    __shared__ float red1[HD], red2[HD];
    if (g < HD) { red1[g] = 0.f; red2[g] = 0.f; }
    __syncthreads();
    if ((g & 63) == 0) {
#pragma unroll
        for (int k = 0; k < HD; ++k) { atomicAdd(&red1[k], s1[k]); atomicAdd(&red2[k], s2[k]); }
    }
    __syncthreads();
    float acc2 = ob2[0];
#pragma unroll
    for (int k = 0; k < HD; ++k) {
        float mu = red1[k] * (1.f / (float)NG);
        float var = red2[k] * (1.f / (float)NG) - mu * mu;
        float zn = (z[k] - mu) * rsqrtf(var + 1e-5f) * gam[k] + bet[k];
        zn = zn > 0.f ? zn : 0.01f * zn;
        acc2 += zn * ow2[k];
    }
    out[g] = acc2;
    out[NG + g] = 1.f / (1.f + __expf(-acc2));
}

extern "C" void kernel_launch(void* const* d_in, const int* in_sizes, int n_in,
                              void* d_out, int out_size, void* d_ws, size_t ws_size,
                              hipStream_t stream)
{
    const float* x     = (const float*)d_in[0];
    const int*   ei    = (const int*)d_in[1];
    const int*   batch = (const int*)d_in[2];
    const float* ea    = (const float*)d_in[3];
    const float* nw1 = (const float*)d_in[5],  *nb1 = (const float*)d_in[6];
    const float* nw2 = (const float*)d_in[7],  *nb2 = (const float*)d_in[8];
    const float* nw3 = (const float*)d_in[9],  *nb3 = (const float*)d_in[10];
    const float* ew1 = (const float*)d_in[11], *eb1 = (const float*)d_in[12];
    const float* ew2 = (const float*)d_in[13], *eb2 = (const float*)d_in[14];
    const float* ew3 = (const float*)d_in[15], *eb3 = (const float*)d_in[16];
    const float* wl  = (const float*)d_in[17], *bl  = (const float*)d_in[18];
    const float* wr  = (const float*)d_in[19], *br  = (const float*)d_in[20];
    const float* we  = (const float*)d_in[21], *att = (const float*)d_in[22];
    const float* gat_bias = (const float*)d_in[23];
    const float* ow1 = (const float*)d_in[24], *ob1 = (const float*)d_in[25];
    const float* gam = (const float*)d_in[26], *bet = (const float*)d_in[27];
    const float* ow2 = (const float*)d_in[28], *ob2 = (const float*)d_in[29];

    const int NBLK_E = NE / 256;            // 15625
    const int NBLK_N = (NN + 255) / 256;    // 977
    const int NBLK_G = NN / 16;             // 15625 (exact)

    // ---- workspace layout (~68 MB, matches R1-proven footprint) ----
    float* ws      = (float*)d_ws;
    float* xl      = ws;                                   // 16N floats
    float* xr      = xl + (size_t)16 * NN;                 // 16N floats (outn aliases this)
    uint2* edval   = (uint2*)(xr + (size_t)16 * NN);       // NE uint2 (32 MB)
    float* partial = (float*)(edval + (size_t)NE);         // NBLK_E*16
    float* ew3p    = partial + (size_t)NBLK_E * HD;        // 256
    float* eb3p    = ew3p + 256;                           // 16
    float* ewm     = eb3p + 16;                            // 16
    int*   bsum    = (int*)(ewm + 16);                     // 256
    int*   bscan   = bsum + 256;                           // 256
    int*   rowptr  = bscan + 256;                          // N
    int*   cursor  = rowptr + (size_t)NN;                  // N
    int*   deg     = cursor + (size_t)NN;                  // N  ---- zero region ----
    unsigned* pooled_u = (unsigned*)(deg + (size_t)NN);    // NG*HD
    float* outn    = xr;                                   // alias (see k_gather note)

    size_t zero_bytes = ((size_t)NN + (size_t)NG * HD) * sizeof(int);
    hipMemsetAsync(deg, 0, zero_bytes, stream);

    k_count<<<NBLK_E, 256, 0, stream>>>(ei, deg);
    k_scan1<<<SCB, 256, 0, stream>>>(deg, bsum);
    k_scan2<<<1, 256, 0, stream>>>(bsum, bscan);
    k_scan3<<<SCB, 256, 0, stream>>>(deg, bscan, rowptr, cursor);
    k_fold<<<1, 256, 0, stream>>>(ew3, eb3, we, ew3p, eb3p);
    k_node<<<NBLK_N, 256, 0, stream>>>(x, nw1, nb1, nw2, nb2, nw3, nb3, wl, bl, wr, br, xl, xr);
    k_edge1<<<NBLK_E, 256, 0, stream>>>(ea, ei, ew1, eb1, ew2, eb2, ew3p, eb3p, att, xl, xr,
                                        cursor, edval, partial);
    k_redp<<<1, 256, 0, stream>>>(partial, NBLK_E, ewm);
    k_gather<<<NBLK_G, 256, 0, stream>>>(edval, rowptr, deg, xl, xr, ewm, att, gat_bias, outn);
    k_pool<<<NBLK_N, 256, 0, stream>>>(outn, batch, pooled_u);
    k_final<<<1, 512, 0, stream>>>(pooled_u, ow1, ob1, gam, bet, ow2, ob2, (float*)d_out);
}

// Round 4
// 1067.010 us; speedup vs baseline: 4.0016x; 1.0278x over previous
//
#include <hip/hip_runtime.h>
#include <hip/hip_fp16.h>
#include <math.h>

#define NN 250000
#define NE 4000000
#define NG 512
#define HD 16
#define SCB 245   // ceil(NN/1024) scan blocks
#define SHIFT 10.0f   // fixed softmax shift (shift-invariant; logits are O(1))

// ---- ordered-uint encoding for float atomicMax ----
__device__ __forceinline__ unsigned enc(float f) {
    unsigned u = __float_as_uint(f);
    return (u & 0x80000000u) ? ~u : (u | 0x80000000u);
}
__device__ __forceinline__ float dec(unsigned u) {
    return __uint_as_float((u & 0x80000000u) ? (u ^ 0x80000000u) : ~u);
}

// ---- fold we into last edge-MLP layer: ew3p = ew3@we, eb3p = eb3@we ----
__global__ __launch_bounds__(256) void k_fold(
    const float* __restrict__ ew3, const float* __restrict__ eb3,
    const float* __restrict__ we, float* __restrict__ ew3p, float* __restrict__ eb3p)
{
    int t = threadIdx.x;
    int j = t >> 4, k = t & 15;
    float acc = 0.f;
    for (int l = 0; l < HD; ++l) acc += ew3[j * HD + l] * we[l * HD + k];
    ew3p[t] = acc;
    if (j == 0) {
        float b = 0.f;
        for (int l = 0; l < HD; ++l) b += eb3[l] * we[l * HD + k];
        eb3p[k] = b;
    }
}

// ---- node MLP + GAT lin_l/lin_r, fused; fp16 output tables ----
__global__ __launch_bounds__(256) void k_node(
    const float* __restrict__ x,
    const float* __restrict__ nw1, const float* __restrict__ nb1,
    const float* __restrict__ nw2, const float* __restrict__ nb2,
    const float* __restrict__ nw3, const float* __restrict__ nb3,
    const float* __restrict__ wl, const float* __restrict__ bl,
    const float* __restrict__ wr, const float* __restrict__ br,
    __half* __restrict__ xl_h, __half* __restrict__ xr_h)
{
    int i = blockIdx.x * 256 + threadIdx.x;
    if (i >= NN) return;
    float4 xv = reinterpret_cast<const float4*>(x)[i];
    float a0 = xv.x, a1 = xv.y, a2 = xv.z, a3 = xv.w;
    float h1[HD], h2[HD], h3[HD];
#pragma unroll
    for (int k = 0; k < HD; ++k) {
        float acc = nb1[k] + a0 * nw1[0 * HD + k] + a1 * nw1[1 * HD + k]
                  + a2 * nw1[2 * HD + k] + a3 * nw1[3 * HD + k];
        h1[k] = fmaxf(acc, 0.f);
    }
#pragma unroll
    for (int k = 0; k < HD; ++k) {
        float acc = nb2[k];
#pragma unroll
        for (int j = 0; j < HD; ++j) acc += h1[j] * nw2[j * HD + k];
        h2[k] = fmaxf(acc, 0.f);
    }
#pragma unroll
    for (int k = 0; k < HD; ++k) {
        float acc = nb3[k];
#pragma unroll
        for (int j = 0; j < HD; ++j) acc += h2[j] * nw3[j * HD + k];
        h3[k] = acc;
    }
    __half lt[HD], rt[HD];
#pragma unroll
    for (int k = 0; k < HD; ++k) {
        float al = bl[k], ar = br[k];
#pragma unroll
        for (int j = 0; j < HD; ++j) { al += h3[j] * wl[j * HD + k]; ar += h3[j] * wr[j * HD + k]; }
        lt[k] = __float2half_rn(al); rt[k] = __float2half_rn(ar);
    }
    uint4* lo = reinterpret_cast<uint4*>(xl_h + (size_t)i * HD);
    uint4* ro = reinterpret_cast<uint4*>(xr_h + (size_t)i * HD);
    lo[0] = reinterpret_cast<uint4*>(lt)[0]; lo[1] = reinterpret_cast<uint4*>(lt)[1];
    ro[0] = reinterpret_cast<uint4*>(rt)[0]; ro[1] = reinterpret_cast<uint4*>(rt)[1];
}

// ---- degree histogram ----
__global__ __launch_bounds__(256) void k_count(const int* __restrict__ ei, int* __restrict__ deg)
{
    int e = blockIdx.x * 256 + threadIdx.x;
    if (e < NE) atomicAdd(&deg[ei[NE + e]], 1);
}

// ---- hierarchical exclusive scan: deg -> rowptr (+cursor copy) ----
__global__ __launch_bounds__(256) void k_scan1(const int* __restrict__ deg, int* __restrict__ bsum)
{
    int b = blockIdx.x, t = threadIdx.x;
    int base = b * 1024 + t * 4;
    int s = 0;
#pragma unroll
    for (int q = 0; q < 4; ++q) { int idx = base + q; if (idx < NN) s += deg[idx]; }
    for (int off = 1; off < 64; off <<= 1) s += __shfl_xor(s, off);
    __shared__ int wsum[4];
    if ((t & 63) == 0) wsum[t >> 6] = s;
    __syncthreads();
    if (t == 0) bsum[b] = wsum[0] + wsum[1] + wsum[2] + wsum[3];
}

__global__ __launch_bounds__(256) void k_scan2(const int* __restrict__ bsum, int* __restrict__ bscan)
{
    int t = threadIdx.x;
    int v = (t < SCB) ? bsum[t] : 0;
    int incl = v;
    int lane = t & 63, w = t >> 6;
    for (int off = 1; off < 64; off <<= 1) { int u = __shfl_up(incl, off); if (lane >= off) incl += u; }
    __shared__ int wsum[4];
    if (lane == 63) wsum[w] = incl;
    __syncthreads();
    int add = 0;
    for (int q = 0; q < w; ++q) add += wsum[q];
    if (t < SCB) bscan[t] = incl + add - v;   // exclusive
}

__global__ __launch_bounds__(256) void k_scan3(const int* __restrict__ deg, const int* __restrict__ bscan,
                                               int* __restrict__ rowptr, int* __restrict__ cursor)
{
    int b = blockIdx.x, t = threadIdx.x;
    int base = b * 1024 + t * 4;
    int d[4]; int s = 0;
#pragma unroll
    for (int q = 0; q < 4; ++q) { int idx = base + q; d[q] = (idx < NN) ? deg[idx] : 0; s += d[q]; }
    int lane = t & 63, w = t >> 6;
    int incl = s;
    for (int off = 1; off < 64; off <<= 1) { int u = __shfl_up(incl, off); if (lane >= off) incl += u; }
    __shared__ int wsum[4];
    if (lane == 63) wsum[w] = incl;
    __syncthreads();
    int add = bscan[b];
    for (int q = 0; q < w; ++q) add += wsum[q];
    int ex = add + incl - s;
#pragma unroll
    for (int q = 0; q < 4; ++q) {
        int idx = base + q;
        if (idx < NN) { rowptr[idx] = ex; cursor[idx] = ex; }
        ex += d[q];
    }
}

// ---- edge MLP (folded) + attention logit, scatter (src,s) into CSR slot ----
__global__ __launch_bounds__(256) void k_edge1(
    const float* __restrict__ ea, const int* __restrict__ ei,
    const float* __restrict__ ew1, const float* __restrict__ eb1,
    const float* __restrict__ ew2, const float* __restrict__ eb2,
    const float* __restrict__ ew3p, const float* __restrict__ eb3p,
    const float* __restrict__ att,
    const __half* __restrict__ xl_h, const __half* __restrict__ xr_h,
    int* __restrict__ cursor, uint2* __restrict__ edval,
    float* __restrict__ partial)
{
    int e = blockIdx.x * 256 + threadIdx.x;
    float ew[HD];
#pragma unroll
    for (int k = 0; k < HD; ++k) ew[k] = 0.f;

    if (e < NE) {
        float4 av0 = reinterpret_cast<const float4*>(ea)[(size_t)e * 2];
        float4 av1 = reinterpret_cast<const float4*>(ea)[(size_t)e * 2 + 1];
        float a[8] = {av0.x, av0.y, av0.z, av0.w, av1.x, av1.y, av1.z, av1.w};
        float t1[HD], t2[HD];
#pragma unroll
        for (int k = 0; k < HD; ++k) {
            float acc = eb1[k];
#pragma unroll
            for (int c = 0; c < 8; ++c) acc += a[c] * ew1[c * HD + k];
            t1[k] = fmaxf(acc, 0.f);
        }
#pragma unroll
        for (int k = 0; k < HD; ++k) {
            float acc = eb2[k];
#pragma unroll
            for (int j = 0; j < HD; ++j) acc += t1[j] * ew2[j * HD + k];
            t2[k] = fmaxf(acc, 0.f);
        }
#pragma unroll
        for (int k = 0; k < HD; ++k) {
            float acc = eb3p[k];
#pragma unroll
            for (int j = 0; j < HD; ++j) acc += t2[j] * ew3p[j * HD + k];
            ew[k] = acc;
        }
        int src = ei[e];
        int dst = ei[NE + e];
        // 32B fp16 rows
        const uint4* lp = reinterpret_cast<const uint4*>(xl_h + (size_t)src * HD);
        const uint4* rp = reinterpret_cast<const uint4*>(xr_h + (size_t)dst * HD);
        uint4 l0 = lp[0], l1 = lp[1], r0 = rp[0], r1 = rp[1];
        __half lt[HD], rt[HD];
        reinterpret_cast<uint4*>(lt)[0] = l0; reinterpret_cast<uint4*>(lt)[1] = l1;
        reinterpret_cast<uint4*>(rt)[0] = r0; reinterpret_cast<uint4*>(rt)[1] = r1;
        float s = 0.f;
#pragma unroll
        for (int k = 0; k < HD; ++k) {
            float t = __half2float(lt[k]) + __half2float(rt[k]) + ew[k];
            t = t > 0.f ? t : 0.2f * t;
            s += t * att[k];
        }
        int pos = atomicAdd(&cursor[dst], 1);
        edval[pos] = make_uint2((unsigned)src, __float_as_uint(s));
    }

    // block-level partial sum of ew (for mean over edges)
    for (int off = 32; off > 0; off >>= 1) {
#pragma unroll
        for (int k = 0; k < HD; ++k) ew[k] += __shfl_xor(ew[k], off);
    }
    __shared__ float bsumf[HD];
    if (threadIdx.x < HD) bsumf[threadIdx.x] = 0.f;
    __syncthreads();
    if ((threadIdx.x & 63) == 0) {
#pragma unroll
        for (int k = 0; k < HD; ++k) atomicAdd(&bsumf[k], ew[k]);
    }
    __syncthreads();
    if (threadIdx.x < HD) partial[(size_t)blockIdx.x * HD + threadIdx.x] = bsumf[threadIdx.x];
}

// ---- reduce block partials -> ewm = mean(e)@we ----
__global__ __launch_bounds__(256) void k_redp(
    const float* __restrict__ partial, int nblk, float* __restrict__ ewm)
{
    __shared__ float red[256];
    int t = threadIdx.x;
    int k = t & 15, c = t >> 4;
    float acc = 0.f;
    for (int b = c; b < nblk; b += 16) acc += partial[(size_t)b * HD + k];
    red[t] = acc;
    __syncthreads();
    if (t < HD) {
        float s = 0.f;
        for (int c2 = 0; c2 < 16; ++c2) s += red[c2 * 16 + t];
        ewm[t] = s * (1.f / (float)NE);
    }
}

// ---- single-pass pull softmax + aggregate + fused segmented max-pool ----
// 16 lanes per node; no per-node max (softmax shift-invariant, logits O(1));
// batch sorted => block's 16 nodes span 1-2 graphs => LDS segmented pool.
__global__ __launch_bounds__(256) void k_gather(
    const uint2* __restrict__ edval, const int* __restrict__ rowptr, const int* __restrict__ deg,
    const __half* __restrict__ xl_h, const __half* __restrict__ xr_h,
    const float* __restrict__ ewm, const float* __restrict__ att,
    const float* __restrict__ gat_bias, const int* __restrict__ batch,
    unsigned* __restrict__ pooled_u)
{
    int t = threadIdx.x;
    int lane = t & 63;
    int sub = lane >> 4;            // node within wave
    int k = lane & 15;              // component
    int wid = t >> 6;               // wave within block
    int i = blockIdx.x * 16 + wid * 4 + sub;   // 15625*16 == NN exactly

    float xlk = __half2float(xl_h[(size_t)i * HD + k]);
    float tv = xlk + __half2float(xr_h[(size_t)i * HD + k]) + ewm[k];
    tv = tv > 0.f ? tv : 0.2f * tv;
    float term = tv * att[k];
#pragma unroll
    for (int off = 1; off < 16; off <<= 1) term += __shfl_xor(term, off);
    float p_self = __expf(term - SHIFT);

    int start = rowptr[i], cnt = deg[i];
    float denl = 0.f;
    float acc = p_self * xlk;
    int basel = lane & 48;          // sub*16
    for (int base = 0; base < cnt; base += 16) {
        int j = base + k;
        int srcv = 0; float pv = 0.f;
        if (j < cnt) {
            uint2 v = edval[start + j];
            srcv = (int)v.x;
            pv = __expf(__uint_as_float(v.y) - SHIFT);
        }
        denl += pv;
#pragma unroll
        for (int tlo = 0; tlo < 16; ++tlo) {
            int src_t = __shfl(srcv, basel + tlo);
            float p_t = __shfl(pv, basel + tlo);
            acc += p_t * __half2float(xl_h[(size_t)src_t * HD + k]);
        }
    }
#pragma unroll
    for (int off = 1; off < 16; off <<= 1) denl += __shfl_xor(denl, off);
    float o = acc / (denl + p_self) + gat_bias[k];

    // ---- fused max-pool ----
    int b = batch[i];
    int g0 = batch[blockIdx.x * 16];      // uniform broadcast load
    __shared__ unsigned pool_s[8][HD];
    __shared__ int flag[8];
    if (t < 128) pool_s[t >> 4][t & 15] = 0u;   // 0 < enc(any finite float)
    if (t < 8) flag[t] = 0;
    __syncthreads();
    int slot = b - g0;                    // >=0 (batch sorted)
    unsigned eo = enc(o);
    if (slot < 8) {
        if (k == 0) flag[slot] = 1;
        atomicMax(&pool_s[slot][k], eo);
    } else {                              // pathological tiny-graph run
        atomicMax(&pooled_u[(size_t)b * HD + k], eo);
    }
    __syncthreads();
    if (t < 128) {
        int sl = t >> 4, kk = t & 15;
        if (flag[sl]) atomicMax(&pooled_u[(size_t)(g0 + sl) * HD + kk], pool_s[sl][kk]);
    }
}

// ---- head MLP + BatchNorm + LeakyReLU + Linear + sigmoid ----
__global__ __launch_bounds__(512) void k_final(
    const unsigned* __restrict__ pooled_u,
    const float* __restrict__ ow1, const float* __restrict__ ob1,
    const float* __restrict__ gam, const float* __restrict__ bet,
    const float* __restrict__ ow2, const float* __restrict__ ob2,
    float* __restrict__ out)
{
    int g = threadIdx.x;
    float pv[HD], z[HD];
#pragma unroll
    for (int k = 0; k < HD; ++k) pv[k] = dec(pooled_u[g * HD + k]);
#pragma unroll
    for (int k = 0; k < HD; ++k) {
        float acc = ob1[k];
#pragma unroll
        for (int j = 0; j < HD; ++j) acc += pv[j] * ow1[j * HD + k];
        z[k] = acc;
    }
    float s1[HD], s2[HD];
#pragma unroll
    for (int k = 0; k < HD; ++k) { s1[k] = z[k]; s2[k] = z[k] * z[k]; }
    for (int off = 32; off > 0; off >>= 1) {
#pragma unroll
        for (int k = 0; k < HD; ++k) {
            s1[k] += __shfl_xor(s1[k], off);
            s2[k] += __shfl_xor(s2[k], off);
        }
    }
    __shared__ float red1[HD], red2[HD];
    if (g < HD) { red1[g] = 0.f; red2[g] = 0.f; }
    __syncthreads();
    if ((g & 63) == 0) {
#pragma unroll
        for (int k = 0; k < HD; ++k) { atomicAdd(&red1[k], s1[k]); atomicAdd(&red2[k], s2[k]); }
    }
    __syncthreads();
    float acc2 = ob2[0];
#pragma unroll
    for (int k = 0; k < HD; ++k) {
        float mu = red1[k] * (1.f / (float)NG);
        float var = red2[k] * (1.f / (float)NG) - mu * mu;
        float zn = (z[k] - mu) * rsqrtf(var + 1e-5f) * gam[k] + bet[k];
        zn = zn > 0.f ? zn : 0.01f * zn;
        acc2 += zn * ow2[k];
    }
    out[g] = acc2;
    out[NG + g] = 1.f / (1.f + __expf(-acc2));
}

extern "C" void kernel_launch(void* const* d_in, const int* in_sizes, int n_in,
                              void* d_out, int out_size, void* d_ws, size_t ws_size,
                              hipStream_t stream)
{
    const float* x     = (const float*)d_in[0];
    const int*   ei    = (const int*)d_in[1];
    const int*   batch = (const int*)d_in[2];
    const float* ea    = (const float*)d_in[3];
    const float* nw1 = (const float*)d_in[5],  *nb1 = (const float*)d_in[6];
    const float* nw2 = (const float*)d_in[7],  *nb2 = (const float*)d_in[8];
    const float* nw3 = (const float*)d_in[9],  *nb3 = (const float*)d_in[10];
    const float* ew1 = (const float*)d_in[11], *eb1 = (const float*)d_in[12];
    const float* ew2 = (const float*)d_in[13], *eb2 = (const float*)d_in[14];
    const float* ew3 = (const float*)d_in[15], *eb3 = (const float*)d_in[16];
    const float* wl  = (const float*)d_in[17], *bl  = (const float*)d_in[18];
    const float* wr  = (const float*)d_in[19], *br  = (const float*)d_in[20];
    const float* we  = (const float*)d_in[21], *att = (const float*)d_in[22];
    const float* gat_bias = (const float*)d_in[23];
    const float* ow1 = (const float*)d_in[24], *ob1 = (const float*)d_in[25];
    const float* gam = (const float*)d_in[26], *bet = (const float*)d_in[27];
    const float* ow2 = (const float*)d_in[28], *ob2 = (const float*)d_in[29];

    const int NBLK_E = NE / 256;            // 15625
    const int NBLK_N = (NN + 255) / 256;    // 977
    const int NBLK_G = NN / 16;             // 15625 (exact)

    // ---- workspace layout (~53 MB) ----
    __half* xl_h   = (__half*)d_ws;                        // 16N halves (8 MB)
    __half* xr_h   = xl_h + (size_t)16 * NN;               // 16N halves (8 MB)
    uint2* edval   = (uint2*)(xr_h + (size_t)16 * NN);     // NE uint2 (32 MB)
    float* partial = (float*)(edval + (size_t)NE);         // NBLK_E*16
    float* ew3p    = partial + (size_t)NBLK_E * HD;        // 256
    float* eb3p    = ew3p + 256;                           // 16
    float* ewm     = eb3p + 16;                            // 16
    int*   bsum    = (int*)(ewm + 16);                     // 256
    int*   bscan   = bsum + 256;                           // 256
    int*   rowptr  = bscan + 256;                          // N
    int*   cursor  = rowptr + (size_t)NN;                  // N
    int*   deg     = cursor + (size_t)NN;                  // N  ---- zero region ----
    unsigned* pooled_u = (unsigned*)(deg + (size_t)NN);    // NG*HD

    size_t zero_bytes = ((size_t)NN + (size_t)NG * HD) * sizeof(int);
    hipMemsetAsync(deg, 0, zero_bytes, stream);

    k_count<<<NBLK_E, 256, 0, stream>>>(ei, deg);
    k_scan1<<<SCB, 256, 0, stream>>>(deg, bsum);
    k_scan2<<<1, 256, 0, stream>>>(bsum, bscan);
    k_scan3<<<SCB, 256, 0, stream>>>(deg, bscan, rowptr, cursor);
    k_fold<<<1, 256, 0, stream>>>(ew3, eb3, we, ew3p, eb3p);
    k_node<<<NBLK_N, 256, 0, stream>>>(x, nw1, nb1, nw2, nb2, nw3, nb3, wl, bl, wr, br, xl_h, xr_h);
    k_edge1<<<NBLK_E, 256, 0, stream>>>(ea, ei, ew1, eb1, ew2, eb2, ew3p, eb3p, att, xl_h, xr_h,
                                        cursor, edval, partial);
    k_redp<<<1, 256, 0, stream>>>(partial, NBLK_E, ewm);
    k_gather<<<NBLK_G, 256, 0, stream>>>(edval, rowptr, deg, xl_h, xr_h, ewm, att, gat_bias,
                                         batch, pooled_u);
    k_final<<<1, 512, 0, stream>>>(pooled_u, ow1, ob1, gam, bet, ow2, ob2, (float*)d_out);
}

// Round 5
// 971.031 us; speedup vs baseline: 4.3971x; 1.0988x over previous
//
#include <hip/hip_runtime.h>
#include <hip/hip_fp16.h>
#include <math.h>

#define NN 250000
#define NE 4000000
#define NG 512
#define HD 16
#define SCB 245   // ceil(NN/1024) scan blocks
#define SHIFT 10.0f   // fixed softmax shift (shift-invariant; logits are O(1))

// ---- ordered-uint encoding for float atomicMax ----
__device__ __forceinline__ unsigned enc(float f) {
    unsigned u = __float_as_uint(f);
    return (u & 0x80000000u) ? ~u : (u | 0x80000000u);
}
__device__ __forceinline__ float dec(unsigned u) {
    return __uint_as_float((u & 0x80000000u) ? (u ^ 0x80000000u) : ~u);
}

// ---- fold we into last edge-MLP layer: ew3p = ew3@we, eb3p = eb3@we ----
__global__ __launch_bounds__(256) void k_fold(
    const float* __restrict__ ew3, const float* __restrict__ eb3,
    const float* __restrict__ we, float* __restrict__ ew3p, float* __restrict__ eb3p)
{
    int t = threadIdx.x;
    int j = t >> 4, k = t & 15;
    float acc = 0.f;
    for (int l = 0; l < HD; ++l) acc += ew3[j * HD + l] * we[l * HD + k];
    ew3p[t] = acc;
    if (j == 0) {
        float b = 0.f;
        for (int l = 0; l < HD; ++l) b += eb3[l] * we[l * HD + k];
        eb3p[k] = b;
    }
}

// ---- node MLP + GAT lin_l/lin_r, fused; fp16 output tables ----
__global__ __launch_bounds__(256) void k_node(
    const float* __restrict__ x,
    const float* __restrict__ nw1, const float* __restrict__ nb1,
    const float* __restrict__ nw2, const float* __restrict__ nb2,
    const float* __restrict__ nw3, const float* __restrict__ nb3,
    const float* __restrict__ wl, const float* __restrict__ bl,
    const float* __restrict__ wr, const float* __restrict__ br,
    __half* __restrict__ xl_h, __half* __restrict__ xr_h)
{
    int i = blockIdx.x * 256 + threadIdx.x;
    if (i >= NN) return;
    float4 xv = reinterpret_cast<const float4*>(x)[i];
    float a0 = xv.x, a1 = xv.y, a2 = xv.z, a3 = xv.w;
    float h1[HD], h2[HD], h3[HD];
#pragma unroll
    for (int k = 0; k < HD; ++k) {
        float acc = nb1[k] + a0 * nw1[0 * HD + k] + a1 * nw1[1 * HD + k]
                  + a2 * nw1[2 * HD + k] + a3 * nw1[3 * HD + k];
        h1[k] = fmaxf(acc, 0.f);
    }
#pragma unroll
    for (int k = 0; k < HD; ++k) {
        float acc = nb2[k];
#pragma unroll
        for (int j = 0; j < HD; ++j) acc += h1[j] * nw2[j * HD + k];
        h2[k] = fmaxf(acc, 0.f);
    }
#pragma unroll
    for (int k = 0; k < HD; ++k) {
        float acc = nb3[k];
#pragma unroll
        for (int j = 0; j < HD; ++j) acc += h2[j] * nw3[j * HD + k];
        h3[k] = acc;
    }
    __half lt[HD], rt[HD];
#pragma unroll
    for (int k = 0; k < HD; ++k) {
        float al = bl[k], ar = br[k];
#pragma unroll
        for (int j = 0; j < HD; ++j) { al += h3[j] * wl[j * HD + k]; ar += h3[j] * wr[j * HD + k]; }
        lt[k] = __float2half_rn(al); rt[k] = __float2half_rn(ar);
    }
    uint4* lo = reinterpret_cast<uint4*>(xl_h + (size_t)i * HD);
    uint4* ro = reinterpret_cast<uint4*>(xr_h + (size_t)i * HD);
    lo[0] = reinterpret_cast<uint4*>(lt)[0]; lo[1] = reinterpret_cast<uint4*>(lt)[1];
    ro[0] = reinterpret_cast<uint4*>(rt)[0]; ro[1] = reinterpret_cast<uint4*>(rt)[1];
}

// ---- degree histogram + within-node rank (rank trick: atomic return value) ----
__global__ __launch_bounds__(256) void k_count(const int* __restrict__ ei,
                                               int* __restrict__ deg,
                                               unsigned short* __restrict__ rank)
{
    int e = blockIdx.x * 256 + threadIdx.x;
    if (e < NE) {
        int r = atomicAdd(&deg[ei[NE + e]], 1);
        rank[e] = (unsigned short)r;   // deg max ~50 << 65536
    }
}

// ---- hierarchical exclusive scan: deg -> rowptr ----
__global__ __launch_bounds__(256) void k_scan1(const int* __restrict__ deg, int* __restrict__ bsum)
{
    int b = blockIdx.x, t = threadIdx.x;
    int base = b * 1024 + t * 4;
    int s = 0;
#pragma unroll
    for (int q = 0; q < 4; ++q) { int idx = base + q; if (idx < NN) s += deg[idx]; }
    for (int off = 1; off < 64; off <<= 1) s += __shfl_xor(s, off);
    __shared__ int wsum[4];
    if ((t & 63) == 0) wsum[t >> 6] = s;
    __syncthreads();
    if (t == 0) bsum[b] = wsum[0] + wsum[1] + wsum[2] + wsum[3];
}

__global__ __launch_bounds__(256) void k_scan2(const int* __restrict__ bsum, int* __restrict__ bscan)
{
    int t = threadIdx.x;
    int v = (t < SCB) ? bsum[t] : 0;
    int incl = v;
    int lane = t & 63, w = t >> 6;
    for (int off = 1; off < 64; off <<= 1) { int u = __shfl_up(incl, off); if (lane >= off) incl += u; }
    __shared__ int wsum[4];
    if (lane == 63) wsum[w] = incl;
    __syncthreads();
    int add = 0;
    for (int q = 0; q < w; ++q) add += wsum[q];
    if (t < SCB) bscan[t] = incl + add - v;   // exclusive
}

__global__ __launch_bounds__(256) void k_scan3(const int* __restrict__ deg, const int* __restrict__ bscan,
                                               int* __restrict__ rowptr)
{
    int b = blockIdx.x, t = threadIdx.x;
    int base = b * 1024 + t * 4;
    int d[4]; int s = 0;
#pragma unroll
    for (int q = 0; q < 4; ++q) { int idx = base + q; d[q] = (idx < NN) ? deg[idx] : 0; s += d[q]; }
    int lane = t & 63, w = t >> 6;
    int incl = s;
    for (int off = 1; off < 64; off <<= 1) { int u = __shfl_up(incl, off); if (lane >= off) incl += u; }
    __shared__ int wsum[4];
    if (lane == 63) wsum[w] = incl;
    __syncthreads();
    int add = bscan[b];
    for (int q = 0; q < w; ++q) add += wsum[q];
    int ex = add + incl - s;
#pragma unroll
    for (int q = 0; q < 4; ++q) {
        int idx = base + q;
        if (idx < NN) rowptr[idx] = ex;
        ex += d[q];
    }
}

// ---- edge MLP (folded) + attention logit, scatter (src,s) -> CSR slot, NO atomics ----
__global__ __launch_bounds__(256) void k_edge1(
    const float* __restrict__ ea, const int* __restrict__ ei,
    const float* __restrict__ ew1, const float* __restrict__ eb1,
    const float* __restrict__ ew2, const float* __restrict__ eb2,
    const float* __restrict__ ew3p, const float* __restrict__ eb3p,
    const float* __restrict__ att,
    const __half* __restrict__ xl_h, const __half* __restrict__ xr_h,
    const int* __restrict__ rowptr, const unsigned short* __restrict__ rank,
    uint2* __restrict__ edval, float* __restrict__ partial)
{
    int e = blockIdx.x * 256 + threadIdx.x;
    float ew[HD];
#pragma unroll
    for (int k = 0; k < HD; ++k) ew[k] = 0.f;

    if (e < NE) {
        // ---- issue all latency-bound loads FIRST, overlap under MLP compute ----
        int src = ei[e];
        int dst = ei[NE + e];
        int rk  = (int)rank[e];                 // coalesced 2B
        int rp  = rowptr[dst];                  // random 4B, L2-resident 1MB table
        const uint4* lp = reinterpret_cast<const uint4*>(xl_h + (size_t)src * HD);
        const uint4* rpx = reinterpret_cast<const uint4*>(xr_h + (size_t)dst * HD);
        uint4 l0 = lp[0], l1 = lp[1], r0 = rpx[0], r1 = rpx[1];
        float4 av0 = reinterpret_cast<const float4*>(ea)[(size_t)e * 2];
        float4 av1 = reinterpret_cast<const float4*>(ea)[(size_t)e * 2 + 1];

        // ---- edge MLP ----
        float a[8] = {av0.x, av0.y, av0.z, av0.w, av1.x, av1.y, av1.z, av1.w};
        float t1[HD], t2[HD];
#pragma unroll
        for (int k = 0; k < HD; ++k) {
            float acc = eb1[k];
#pragma unroll
            for (int c = 0; c < 8; ++c) acc += a[c] * ew1[c * HD + k];
            t1[k] = fmaxf(acc, 0.f);
        }
#pragma unroll
        for (int k = 0; k < HD; ++k) {
            float acc = eb2[k];
#pragma unroll
            for (int j = 0; j < HD; ++j) acc += t1[j] * ew2[j * HD + k];
            t2[k] = fmaxf(acc, 0.f);
        }
#pragma unroll
        for (int k = 0; k < HD; ++k) {
            float acc = eb3p[k];
#pragma unroll
            for (int j = 0; j < HD; ++j) acc += t2[j] * ew3p[j * HD + k];
            ew[k] = acc;
        }

        __half lt[HD], rt[HD];
        reinterpret_cast<uint4*>(lt)[0] = l0; reinterpret_cast<uint4*>(lt)[1] = l1;
        reinterpret_cast<uint4*>(rt)[0] = r0; reinterpret_cast<uint4*>(rt)[1] = r1;
        float s = 0.f;
#pragma unroll
        for (int k = 0; k < HD; ++k) {
            float t = __half2float(lt[k]) + __half2float(rt[k]) + ew[k];
            t = t > 0.f ? t : 0.2f * t;
            s += t * att[k];
        }
        int pos = rp + rk;                      // CSR slot, no atomic
        edval[pos] = make_uint2((unsigned)src, __float_as_uint(s));
    }

    // block-level partial sum of ew (for mean over edges)
    for (int off = 32; off > 0; off >>= 1) {
#pragma unroll
        for (int k = 0; k < HD; ++k) ew[k] += __shfl_xor(ew[k], off);
    }
    __shared__ float bsumf[HD];
    if (threadIdx.x < HD) bsumf[threadIdx.x] = 0.f;
    __syncthreads();
    if ((threadIdx.x & 63) == 0) {
#pragma unroll
        for (int k = 0; k < HD; ++k) atomicAdd(&bsumf[k], ew[k]);
    }
    __syncthreads();
    if (threadIdx.x < HD) partial[(size_t)blockIdx.x * HD + threadIdx.x] = bsumf[threadIdx.x];
}

// ---- reduce block partials -> ewm = mean(e)@we ----
__global__ __launch_bounds__(256) void k_redp(
    const float* __restrict__ partial, int nblk, float* __restrict__ ewm)
{
    __shared__ float red[256];
    int t = threadIdx.x;
    int k = t & 15, c = t >> 4;
    float acc = 0.f;
    for (int b = c; b < nblk; b += 16) acc += partial[(size_t)b * HD + k];
    red[t] = acc;
    __syncthreads();
    if (t < HD) {
        float s = 0.f;
        for (int c2 = 0; c2 < 16; ++c2) s += red[c2 * 16 + t];
        ewm[t] = s * (1.f / (float)NE);
    }
}

// ---- single-pass pull softmax + aggregate + fused segmented max-pool ----
__global__ __launch_bounds__(256) void k_gather(
    const uint2* __restrict__ edval, const int* __restrict__ rowptr, const int* __restrict__ deg,
    const __half* __restrict__ xl_h, const __half* __restrict__ xr_h,
    const float* __restrict__ ewm, const float* __restrict__ att,
    const float* __restrict__ gat_bias, const int* __restrict__ batch,
    unsigned* __restrict__ pooled_u)
{
    int t = threadIdx.x;
    int lane = t & 63;
    int sub = lane >> 4;            // node within wave
    int k = lane & 15;              // component
    int wid = t >> 6;               // wave within block
    int i = blockIdx.x * 16 + wid * 4 + sub;   // 15625*16 == NN exactly

    float xlk = __half2float(xl_h[(size_t)i * HD + k]);
    float tv = xlk + __half2float(xr_h[(size_t)i * HD + k]) + ewm[k];
    tv = tv > 0.f ? tv : 0.2f * tv;
    float term = tv * att[k];
#pragma unroll
    for (int off = 1; off < 16; off <<= 1) term += __shfl_xor(term, off);
    float p_self = __expf(term - SHIFT);

    int start = rowptr[i], cnt = deg[i];
    float denl = 0.f;
    float acc = p_self * xlk;
    int basel = lane & 48;          // sub*16
    for (int base = 0; base < cnt; base += 16) {
        int j = base + k;
        int srcv = 0; float pv = 0.f;
        if (j < cnt) {
            uint2 v = edval[start + j];
            srcv = (int)v.x;
            pv = __expf(__uint_as_float(v.y) - SHIFT);
        }
        denl += pv;
#pragma unroll
        for (int tlo = 0; tlo < 16; ++tlo) {
            int src_t = __shfl(srcv, basel + tlo);
            float p_t = __shfl(pv, basel + tlo);
            acc += p_t * __half2float(xl_h[(size_t)src_t * HD + k]);
        }
    }
#pragma unroll
    for (int off = 1; off < 16; off <<= 1) denl += __shfl_xor(denl, off);
    float o = acc / (denl + p_self) + gat_bias[k];

    // ---- fused max-pool (batch sorted => block spans few graphs) ----
    int b = batch[i];
    int g0 = batch[blockIdx.x * 16];
    __shared__ unsigned pool_s[8][HD];
    __shared__ int flag[8];
    if (t < 128) pool_s[t >> 4][t & 15] = 0u;   // 0 < enc(any finite float)
    if (t < 8) flag[t] = 0;
    __syncthreads();
    int slot = b - g0;
    unsigned eo = enc(o);
    if (slot < 8) {
        if (k == 0) flag[slot] = 1;
        atomicMax(&pool_s[slot][k], eo);
    } else {
        atomicMax(&pooled_u[(size_t)b * HD + k], eo);
    }
    __syncthreads();
    if (t < 128) {
        int sl = t >> 4, kk = t & 15;
        if (flag[sl]) atomicMax(&pooled_u[(size_t)(g0 + sl) * HD + kk], pool_s[sl][kk]);
    }
}

// ---- head MLP + BatchNorm + LeakyReLU + Linear + sigmoid ----
__global__ __launch_bounds__(512) void k_final(
    const unsigned* __restrict__ pooled_u,
    const float* __restrict__ ow1, const float* __restrict__ ob1,
    const float* __restrict__ gam, const float* __restrict__ bet,
    const float* __restrict__ ow2, const float* __restrict__ ob2,
    float* __restrict__ out)
{
    int g = threadIdx.x;
    float pv[HD], z[HD];
#pragma unroll
    for (int k = 0; k < HD; ++k) pv[k] = dec(pooled_u[g * HD + k]);
#pragma unroll
    for (int k = 0; k < HD; ++k) {
        float acc = ob1[k];
#pragma unroll
        for (int j = 0; j < HD; ++j) acc += pv[j] * ow1[j * HD + k];
        z[k] = acc;
    }
    float s1[HD], s2[HD];
#pragma unroll
    for (int k = 0; k < HD; ++k) { s1[k] = z[k]; s2[k] = z[k] * z[k]; }
    for (int off = 32; off > 0; off >>= 1) {
#pragma unroll
        for (int k = 0; k < HD; ++k) {
            s1[k] += __shfl_xor(s1[k], off);
            s2[k] += __shfl_xor(s2[k], off);
        }
    }
    __shared__ float red1[HD], red2[HD];
    if (g < HD) { red1[g] = 0.f; red2[g] = 0.f; }
    __syncthreads();
    if ((g & 63) == 0) {
#pragma unroll
        for (int k = 0; k < HD; ++k) { atomicAdd(&red1[k], s1[k]); atomicAdd(&red2[k], s2[k]); }
    }
    __syncthreads();
    float acc2 = ob2[0];
#pragma unroll
    for (int k = 0; k < HD; ++k) {
        float mu = red1[k] * (1.f / (float)NG);
        float var = red2[k] * (1.f / (float)NG) - mu * mu;
        float zn = (z[k] - mu) * rsqrtf(var + 1e-5f) * gam[k] + bet[k];
        zn = zn > 0.f ? zn : 0.01f * zn;
        acc2 += zn * ow2[k];
    }
    out[g] = acc2;
    out[NG + g] = 1.f / (1.f + __expf(-acc2));
}

extern "C" void kernel_launch(void* const* d_in, const int* in_sizes, int n_in,
                              void* d_out, int out_size, void* d_ws, size_t ws_size,
                              hipStream_t stream)
{
    const float* x     = (const float*)d_in[0];
    const int*   ei    = (const int*)d_in[1];
    const int*   batch = (const int*)d_in[2];
    const float* ea    = (const float*)d_in[3];
    const float* nw1 = (const float*)d_in[5],  *nb1 = (const float*)d_in[6];
    const float* nw2 = (const float*)d_in[7],  *nb2 = (const float*)d_in[8];
    const float* nw3 = (const float*)d_in[9],  *nb3 = (const float*)d_in[10];
    const float* ew1 = (const float*)d_in[11], *eb1 = (const float*)d_in[12];
    const float* ew2 = (const float*)d_in[13], *eb2 = (const float*)d_in[14];
    const float* ew3 = (const float*)d_in[15], *eb3 = (const float*)d_in[16];
    const float* wl  = (const float*)d_in[17], *bl  = (const float*)d_in[18];
    const float* wr  = (const float*)d_in[19], *br  = (const float*)d_in[20];
    const float* we  = (const float*)d_in[21], *att = (const float*)d_in[22];
    const float* gat_bias = (const float*)d_in[23];
    const float* ow1 = (const float*)d_in[24], *ob1 = (const float*)d_in[25];
    const float* gam = (const float*)d_in[26], *bet = (const float*)d_in[27];
    const float* ow2 = (const float*)d_in[28], *ob2 = (const float*)d_in[29];

    const int NBLK_E = NE / 256;            // 15625
    const int NBLK_N = (NN + 255) / 256;    // 977
    const int NBLK_G = NN / 16;             // 15625 (exact)

    // ---- workspace layout (~59 MB) ----
    __half* xl_h   = (__half*)d_ws;                        // 16N halves (8 MB)
    __half* xr_h   = xl_h + (size_t)16 * NN;               // 16N halves (8 MB)
    uint2* edval   = (uint2*)(xr_h + (size_t)16 * NN);     // NE uint2 (32 MB)
    float* partial = (float*)(edval + (size_t)NE);         // NBLK_E*16 (1 MB)
    float* ew3p    = partial + (size_t)NBLK_E * HD;        // 256
    float* eb3p    = ew3p + 256;                           // 16
    float* ewm     = eb3p + 16;                            // 16
    int*   bsum    = (int*)(ewm + 16);                     // 256
    int*   bscan   = bsum + 256;                           // 256
    int*   rowptr  = bscan + 256;                          // N (1 MB)
    unsigned short* rank = (unsigned short*)(rowptr + (size_t)NN);  // NE u16 (8 MB)
    int*   deg     = (int*)(rank + (size_t)NE);            // N  ---- zero region ----
    unsigned* pooled_u = (unsigned*)(deg + (size_t)NN);    // NG*HD

    size_t zero_bytes = ((size_t)NN + (size_t)NG * HD) * sizeof(int);
    hipMemsetAsync(deg, 0, zero_bytes, stream);

    k_count<<<NBLK_E, 256, 0, stream>>>(ei, deg, rank);
    k_scan1<<<SCB, 256, 0, stream>>>(deg, bsum);
    k_scan2<<<1, 256, 0, stream>>>(bsum, bscan);
    k_scan3<<<SCB, 256, 0, stream>>>(deg, bscan, rowptr);
    k_fold<<<1, 256, 0, stream>>>(ew3, eb3, we, ew3p, eb3p);
    k_node<<<NBLK_N, 256, 0, stream>>>(x, nw1, nb1, nw2, nb2, nw3, nb3, wl, bl, wr, br, xl_h, xr_h);
    k_edge1<<<NBLK_E, 256, 0, stream>>>(ea, ei, ew1, eb1, ew2, eb2, ew3p, eb3p, att, xl_h, xr_h,
                                        rowptr, rank, edval, partial);
    k_redp<<<1, 256, 0, stream>>>(partial, NBLK_E, ewm);
    k_gather<<<NBLK_G, 256, 0, stream>>>(edval, rowptr, deg, xl_h, xr_h, ewm, att, gat_bias,
                                         batch, pooled_u);
    k_final<<<1, 512, 0, stream>>>(pooled_u, ow1, ob1, gam, bet, ow2, ob2, (float*)d_out);
}